// Round 3
// baseline (818.500 us; speedup 1.0000x reference)
//
#include <hip/hip_runtime.h>
#include <hip/hip_bf16.h>
#include <cstdint>
#include <cstddef>

#define N_NODES 50000
#define DIM 512
#define N_EDGES 1600000
#define NB N_NODES

typedef __bf16 bf16;
typedef __bf16 bf16x8 __attribute__((ext_vector_type(8)));
typedef __bf16 bf16x4 __attribute__((ext_vector_type(4)));
typedef float floatx4 __attribute__((ext_vector_type(4)));
typedef float floatx2 __attribute__((ext_vector_type(2)));
typedef unsigned int uintx2 __attribute__((ext_vector_type(2)));
typedef unsigned int uintx4 __attribute__((ext_vector_type(4)));

// ---------------- cast fp32 -> bf16 (W only) ----------------
__global__ void cast_kernel(const float* __restrict__ in, bf16* __restrict__ out, int n4) {
    int i = blockIdx.x * blockDim.x + threadIdx.x;
    if (i >= n4) return;
    float4 v = reinterpret_cast<const float4*>(in)[i];
    bf16x4 o;
    o[0] = (bf16)v.x; o[1] = (bf16)v.y; o[2] = (bf16)v.z; o[3] = (bf16)v.w;
    reinterpret_cast<bf16x4*>(out)[i] = o;
}

// ---------------- CSR build (plain row buckets) ----------------
__global__ void hist_kernel(const int* __restrict__ rows, int* __restrict__ cnt, int E) {
    int i = blockIdx.x * blockDim.x + threadIdx.x;
    if (i < E) atomicAdd(&cnt[rows[i]], 1);
}

__global__ __launch_bounds__(1024) void scanA_kernel(const int* __restrict__ cnt,
                                                     int* __restrict__ row_start,
                                                     int* __restrict__ blksum, int n) {
    __shared__ int s[1024];
    const int t = threadIdx.x;
    int i = blockIdx.x * 1024 + t;
    int v = (i < n) ? cnt[i] : 0;
    s[t] = v;
    __syncthreads();
    for (int off = 1; off < 1024; off <<= 1) {
        int u = (t >= off) ? s[t - off] : 0;
        __syncthreads();
        s[t] += u;
        __syncthreads();
    }
    if (i < n) row_start[i] = s[t] - v;  // exclusive within block
    if (t == 1023) blksum[blockIdx.x] = s[1023];
}

__global__ __launch_bounds__(1024) void scanB_kernel(const int* __restrict__ blksum,
                                                     int* __restrict__ blkoff, int nb) {
    __shared__ int s[1024];
    const int t = threadIdx.x;
    const int base = t * 2;
    int a = (base < nb) ? blksum[base] : 0;
    int b = (base + 1 < nb) ? blksum[base + 1] : 0;
    s[t] = a + b;
    __syncthreads();
    for (int off = 1; off < 1024; off <<= 1) {
        int u = (t >= off) ? s[t - off] : 0;
        __syncthreads();
        s[t] += u;
        __syncthreads();
    }
    int excl = (t == 0) ? 0 : s[t - 1];
    if (base < nb) blkoff[base] = excl;
    if (base + 1 < nb) blkoff[base + 1] = excl + a;
}

__global__ __launch_bounds__(1024) void scanC_kernel(int* __restrict__ row_start,
                                                     const int* __restrict__ blkoff,
                                                     int* __restrict__ cursor, int n) {
    int i = blockIdx.x * 1024 + threadIdx.x;
    if (i >= n) return;
    int v = row_start[i] + blkoff[i >> 10];
    row_start[i] = v;
    cursor[i] = v;
    if (i == n - 1) row_start[n] = N_EDGES;
}

__global__ void scatter_kernel(const int* __restrict__ rows, const int* __restrict__ cols,
                               const float* __restrict__ vals, int* __restrict__ cursor,
                               unsigned long long* __restrict__ ecv, int E) {
    int i = blockIdx.x * blockDim.x + threadIdx.x;
    if (i >= E) return;
    int r = rows[i];
    int p = atomicAdd(&cursor[r], 1);
    unsigned long long packed =
        (unsigned long long)(unsigned int)cols[i] |
        ((unsigned long long)(unsigned int)__float_as_uint(vals[i]) << 32);
    __builtin_nontemporal_store(packed, &ecv[p]);
}

// ---------------- GEMM v2: full-row blocks, A read fp32 direct (no cast, no reuse) ----
// y[128 rows][512 cols] per block; 512 threads = 8 waves as 4(m) x 2(n);
// wave-tile 32x256; W staged bf16 per 32-k chunk via global_load_lds.
__global__ __launch_bounds__(512) void gemm_kernel(const float* __restrict__ A,
                                                   const bf16* __restrict__ B,
                                                   bf16* __restrict__ C) {
    __shared__ bf16 lB[512 * 32];  // 32 KB
    const int t = threadIdx.x;
    const int wave = t >> 6;
    const int lane = t & 63;
    const int rowBase = blockIdx.x * 128;
    const int wm = (wave >> 1) * 32;       // 4 m-groups of 32 rows
    const int wn = (wave & 1) * 256;       // 2 n-halves of 256 cols
    const int l15 = lane & 15;
    const int koct = (lane >> 4) * 8;      // k offset (8 elems) for frags

    floatx4 acc[2][16] = {};

    for (int k0 = 0; k0 < DIM; k0 += 32) {
        // stage W[0:512][k0:k0+32] -> lB[n][32], 4 issues of 512 lanes x 16B
#pragma unroll
        for (int j = 0; j < 4; j++) {
            int idx = j * 512 + t;               // 0..2047
            int n = idx >> 2;
            int ko = (idx & 3) * 8;
            const bf16* g = B + (size_t)n * DIM + k0 + ko;
            bf16* l = lB + (size_t)j * 4096 + wave * 512;  // wave-uniform base
            __builtin_amdgcn_global_load_lds(
                (const __attribute__((address_space(1))) void*)g,
                (__attribute__((address_space(3))) void*)l, 16, 0, 0);
        }
        // A fragments: direct fp32 global load + cvt (each (row,k) used exactly once)
        bf16x8 af[2];
#pragma unroll
        for (int i = 0; i < 2; i++) {
            int row = rowBase + wm + i * 16 + l15;
            if (row > N_NODES - 1) row = N_NODES - 1;
            const float* ga = A + (size_t)row * DIM + k0 + koct;
            float4 fa = *reinterpret_cast<const float4*>(ga);
            float4 fb = *reinterpret_cast<const float4*>(ga + 4);
            bf16x8 v;
            v[0] = (bf16)fa.x; v[1] = (bf16)fa.y; v[2] = (bf16)fa.z; v[3] = (bf16)fa.w;
            v[4] = (bf16)fb.x; v[5] = (bf16)fb.y; v[6] = (bf16)fb.z; v[7] = (bf16)fb.w;
            af[i] = v;
        }
        __syncthreads();   // staging complete
#pragma unroll
        for (int nt = 0; nt < 16; nt++) {
            const bf16* bp = lB + (size_t)(wn + nt * 16 + l15) * 32 + koct;
            bf16x8 bf = *reinterpret_cast<const bf16x8*>(bp);
            acc[0][nt] = __builtin_amdgcn_mfma_f32_16x16x32_bf16(af[0], bf, acc[0][nt], 0, 0, 0);
            acc[1][nt] = __builtin_amdgcn_mfma_f32_16x16x32_bf16(af[1], bf, acc[1][nt], 0, 0, 0);
        }
        __syncthreads();   // keep next staging from clobbering
    }
    // epilogue: D row = (lane>>4)*4+reg, col = lane&15
    const int rquad = (lane >> 4) * 4;
#pragma unroll
    for (int i = 0; i < 2; i++) {
#pragma unroll
        for (int reg = 0; reg < 4; reg++) {
            int gr = rowBase + wm + i * 16 + rquad + reg;
            if (gr >= N_NODES) continue;
#pragma unroll
            for (int nt = 0; nt < 16; nt++) {
                int gc = wn + nt * 16 + l15;
                C[(size_t)gr * DIM + gc] = (bf16)acc[i][nt][reg];
            }
        }
    }
}

// ---------------- SpMM half-pass: wave per row, lane owns 4 dims of one half ----------------
__device__ __forceinline__ float blo(uint32_t w) { return __uint_as_float(w << 16); }
__device__ __forceinline__ float bhi(uint32_t w) { return __uint_as_float(w & 0xffff0000u); }

__device__ __forceinline__ void fmac4(float* acc, unsigned long long e, const uintx2& w) {
    float v = __uint_as_float((uint32_t)(e >> 32));
    acc[0] += v * blo(w[0]); acc[1] += v * bhi(w[0]);
    acc[2] += v * blo(w[1]); acc[3] += v * bhi(w[1]);
}

__global__ __launch_bounds__(256) void spmm_kernel(const int* __restrict__ row_start,
                                                   const unsigned long long* __restrict__ ecv,
                                                   const bf16* __restrict__ y,
                                                   float* __restrict__ y2, int dimOff) {
    const int wave = threadIdx.x >> 6;
    const int lane = threadIdx.x & 63;
    const int r = blockIdx.x * 4 + wave;   // grid = 12500 exactly
    const int s = row_start[r];
    const int e = row_start[r + 1];
    float acc[4] = {0.f, 0.f, 0.f, 0.f};
    // per-column gather: 8 bytes (4 bf16) at byte offset dimOff*2 + lane*8
    const uintx2* yb = reinterpret_cast<const uintx2*>(
        reinterpret_cast<const char*>(y) + (size_t)dimOff * 2 + (size_t)lane * 8);

    int i = s;
    for (; i + 7 < e; i += 8) {
        unsigned long long e0 = __builtin_nontemporal_load(&ecv[i]);
        unsigned long long e1 = __builtin_nontemporal_load(&ecv[i + 1]);
        unsigned long long e2 = __builtin_nontemporal_load(&ecv[i + 2]);
        unsigned long long e3 = __builtin_nontemporal_load(&ecv[i + 3]);
        unsigned long long e4 = __builtin_nontemporal_load(&ecv[i + 4]);
        unsigned long long e5 = __builtin_nontemporal_load(&ecv[i + 5]);
        unsigned long long e6 = __builtin_nontemporal_load(&ecv[i + 6]);
        unsigned long long e7 = __builtin_nontemporal_load(&ecv[i + 7]);
        uintx2 w0 = yb[(size_t)(uint32_t)e0 * 128];
        uintx2 w1 = yb[(size_t)(uint32_t)e1 * 128];
        uintx2 w2 = yb[(size_t)(uint32_t)e2 * 128];
        uintx2 w3 = yb[(size_t)(uint32_t)e3 * 128];
        uintx2 w4 = yb[(size_t)(uint32_t)e4 * 128];
        uintx2 w5 = yb[(size_t)(uint32_t)e5 * 128];
        uintx2 w6 = yb[(size_t)(uint32_t)e6 * 128];
        uintx2 w7 = yb[(size_t)(uint32_t)e7 * 128];
        fmac4(acc, e0, w0); fmac4(acc, e1, w1); fmac4(acc, e2, w2); fmac4(acc, e3, w3);
        fmac4(acc, e4, w4); fmac4(acc, e5, w5); fmac4(acc, e6, w6); fmac4(acc, e7, w7);
    }
    for (; i < e; i++) {
        unsigned long long e0 = __builtin_nontemporal_load(&ecv[i]);
        uintx2 w0 = yb[(size_t)(uint32_t)e0 * 128];
        fmac4(acc, e0, w0);
    }
    floatx4 o; o[0] = acc[0]; o[1] = acc[1]; o[2] = acc[2]; o[3] = acc[3];
    floatx4* out = reinterpret_cast<floatx4*>(y2 + (size_t)r * DIM + dimOff + lane * 4);
    __builtin_nontemporal_store(o, out);
}

// ---------------- reduction: colsum[512] + total sum of squares ----------------
__global__ __launch_bounds__(256) void reduce_kernel(const float* __restrict__ y2,
                                                     float* __restrict__ colsum,
                                                     float* __restrict__ totsq) {
    const int t = threadIdx.x;
    const int d2 = t * 2;
    float c0 = 0.f, c1 = 0.f, sq = 0.f;
    for (int r = blockIdx.x; r < N_NODES; r += gridDim.x) {
        floatx2 v = __builtin_nontemporal_load(
            reinterpret_cast<const floatx2*>(y2 + (size_t)r * DIM + d2));
        c0 += v[0]; c1 += v[1];
        sq += v[0] * v[0] + v[1] * v[1];
    }
    atomicAdd(&colsum[d2], c0);
    atomicAdd(&colsum[d2 + 1], c1);
    __shared__ float ssq[256];
    ssq[t] = sq;
    __syncthreads();
    for (int off = 128; off > 0; off >>= 1) {
        if (t < off) ssq[t] += ssq[t + off];
        __syncthreads();
    }
    if (t == 0) atomicAdd(totsq, ssq[0]);
}

__global__ void scalar_kernel(const float* __restrict__ colsum, const float* __restrict__ totsq,
                              const float* __restrict__ scale, float* __restrict__ sfac) {
    __shared__ float sm[512];
    const int t = threadIdx.x;
    float mu = colsum[t] * (1.0f / N_NODES);
    sm[t] = mu * mu;
    __syncthreads();
    for (int off = 256; off > 0; off >>= 1) {
        if (t < off) sm[t] += sm[t + off];
        __syncthreads();
    }
    if (t == 0) {
        float var = totsq[0] * (1.0f / N_NODES) - sm[0];
        sfac[0] = rsqrtf(var) * (1.0f + scale[0]) * sqrtf((float)DIM);
    }
}

// ---------------- final: out = relu((y2 - mu) * s) + x  (in place on d_out) ----------------
__global__ void final_kernel(float* __restrict__ y2, const float* __restrict__ x,
                             const float* __restrict__ colsum, const float* __restrict__ sfac,
                             int n4) {
    int i = blockIdx.x * blockDim.x + threadIdx.x;
    if (i >= n4) return;
    const float invN = 1.0f / N_NODES;
    floatx4 v = __builtin_nontemporal_load(reinterpret_cast<floatx4*>(y2) + i);
    floatx4 xv = __builtin_nontemporal_load(reinterpret_cast<const floatx4*>(x) + i);
    float4 mu = reinterpret_cast<const float4*>(colsum)[i & 127];
    float s = sfac[0];
    v[0] = fmaxf((v[0] - mu.x * invN) * s, 0.0f) + xv[0];
    v[1] = fmaxf((v[1] - mu.y * invN) * s, 0.0f) + xv[1];
    v[2] = fmaxf((v[2] - mu.z * invN) * s, 0.0f) + xv[2];
    v[3] = fmaxf((v[3] - mu.w * invN) * s, 0.0f) + xv[3];
    __builtin_nontemporal_store(v, reinterpret_cast<floatx4*>(y2) + i);
}

extern "C" void kernel_launch(void* const* d_in, const int* in_sizes, int n_in,
                              void* d_out, int out_size, void* d_ws, size_t ws_size,
                              hipStream_t stream) {
    const float* x        = (const float*)d_in[0];
    const int*   adj_rows = (const int*)d_in[1];
    const int*   adj_cols = (const int*)d_in[2];
    const float* adj_vals = (const float*)d_in[3];
    const float* weight   = (const float*)d_in[4];
    const float* scale    = (const float*)d_in[5];
    float* out = (float*)d_out;  // doubles as y2 buffer

    char* ws = (char*)d_ws;
    size_t off = 0;
    auto alloc = [&](size_t b) {
        char* p = ws + off;
        off += (b + 255) & ~(size_t)255;
        return p;
    };
    const int nblk = (NB + 1023) / 1024;  // 49
    bf16*  y         = (bf16*)alloc((size_t)N_NODES * DIM * 2);        // 51.2 MB
    unsigned long long* ecv = (unsigned long long*)alloc((size_t)N_EDGES * 8);  // 12.8 MB
    bf16*  Wb        = (bf16*)alloc((size_t)DIM * DIM * 2);            // 0.5 MB
    int*   cnt       = (int*)alloc((size_t)NB * 4);                    // 200 KB
    int*   cursor    = cnt;   // ALIAS: cnt dead after scanA; cursor born in scanC
    int*   row_start = (int*)alloc((size_t)(NB + 1) * 4);
    int*   blksum    = (int*)alloc((size_t)nblk * 4);
    int*   blkoff    = (int*)alloc((size_t)nblk * 4);
    float* stats     = (float*)alloc(514 * 4);  // colsum[512] | totsq | sfac
    float* colsum    = stats;
    float* totsq     = stats + 512;
    float* sfac      = stats + 513;
    (void)ws_size; (void)in_sizes; (void)n_in; (void)out_size;

    hipMemsetAsync(cnt, 0, (size_t)NB * 4, stream);
    hipMemsetAsync(stats, 0, 514 * 4, stream);

    const int n4x = N_NODES * DIM / 4;  // 6,400,000
    const int n4w = DIM * DIM / 4;      // 65,536
    cast_kernel<<<(n4w + 255) / 256, 256, 0, stream>>>(weight, Wb, n4w);

    hist_kernel<<<(N_EDGES + 255) / 256, 256, 0, stream>>>(adj_rows, cnt, N_EDGES);
    scanA_kernel<<<nblk, 1024, 0, stream>>>(cnt, row_start, blksum, NB);
    scanB_kernel<<<1, 1024, 0, stream>>>(blksum, blkoff, nblk);
    scanC_kernel<<<nblk, 1024, 0, stream>>>(row_start, blkoff, cursor, NB);
    scatter_kernel<<<(N_EDGES + 255) / 256, 256, 0, stream>>>(adj_rows, adj_cols, adj_vals,
                                                              cursor, ecv, N_EDGES);

    gemm_kernel<<<(N_NODES + 127) / 128, 512, 0, stream>>>(x, Wb, y);

    spmm_kernel<<<N_NODES / 4, 256, 0, stream>>>(row_start, ecv, y, out, 0);
    spmm_kernel<<<N_NODES / 4, 256, 0, stream>>>(row_start, ecv, y, out, 256);

    reduce_kernel<<<256, 256, 0, stream>>>(out, colsum, totsq);
    scalar_kernel<<<1, 512, 0, stream>>>(colsum, totsq, scale, sfac);
    final_kernel<<<(n4x + 255) / 256, 256, 0, stream>>>(out, x, colsum, sfac, n4x);
}

// Round 4
// 785.656 us; speedup vs baseline: 1.0418x; 1.0418x over previous
//
#include <hip/hip_runtime.h>
#include <hip/hip_bf16.h>
#include <cstdint>
#include <cstddef>

#define N_NODES 50000
#define DIM 512
#define N_EDGES 1600000
#define NB N_NODES

typedef __bf16 bf16;
typedef __bf16 bf16x8 __attribute__((ext_vector_type(8)));
typedef __bf16 bf16x4 __attribute__((ext_vector_type(4)));
typedef float floatx4 __attribute__((ext_vector_type(4)));
typedef float floatx2 __attribute__((ext_vector_type(2)));

// ---------------- cast fp32 -> bf16 (W only) ----------------
__global__ void cast_kernel(const float* __restrict__ in, bf16* __restrict__ out, int n4) {
    int i = blockIdx.x * blockDim.x + threadIdx.x;
    if (i >= n4) return;
    float4 v = reinterpret_cast<const float4*>(in)[i];
    bf16x4 o;
    o[0] = (bf16)v.x; o[1] = (bf16)v.y; o[2] = (bf16)v.z; o[3] = (bf16)v.w;
    reinterpret_cast<bf16x4*>(out)[i] = o;
}

// ---------------- CSR build (plain row buckets) ----------------
__global__ void hist_kernel(const int* __restrict__ rows, int* __restrict__ cnt, int E) {
    int i = blockIdx.x * blockDim.x + threadIdx.x;
    if (i < E) atomicAdd(&cnt[rows[i]], 1);
}

__global__ __launch_bounds__(1024) void scanA_kernel(const int* __restrict__ cnt,
                                                     int* __restrict__ row_start,
                                                     int* __restrict__ blksum, int n) {
    __shared__ int s[1024];
    const int t = threadIdx.x;
    int i = blockIdx.x * 1024 + t;
    int v = (i < n) ? cnt[i] : 0;
    s[t] = v;
    __syncthreads();
    for (int off = 1; off < 1024; off <<= 1) {
        int u = (t >= off) ? s[t - off] : 0;
        __syncthreads();
        s[t] += u;
        __syncthreads();
    }
    if (i < n) row_start[i] = s[t] - v;  // exclusive within block
    if (t == 1023) blksum[blockIdx.x] = s[1023];
}

__global__ __launch_bounds__(1024) void scanB_kernel(const int* __restrict__ blksum,
                                                     int* __restrict__ blkoff, int nb) {
    __shared__ int s[1024];
    const int t = threadIdx.x;
    const int base = t * 2;
    int a = (base < nb) ? blksum[base] : 0;
    int b = (base + 1 < nb) ? blksum[base + 1] : 0;
    s[t] = a + b;
    __syncthreads();
    for (int off = 1; off < 1024; off <<= 1) {
        int u = (t >= off) ? s[t - off] : 0;
        __syncthreads();
        s[t] += u;
        __syncthreads();
    }
    int excl = (t == 0) ? 0 : s[t - 1];
    if (base < nb) blkoff[base] = excl;
    if (base + 1 < nb) blkoff[base + 1] = excl + a;
}

__global__ __launch_bounds__(1024) void scanC_kernel(int* __restrict__ row_start,
                                                     const int* __restrict__ blkoff,
                                                     int* __restrict__ cursor, int n) {
    int i = blockIdx.x * 1024 + threadIdx.x;
    if (i >= n) return;
    int v = row_start[i] + blkoff[i >> 10];
    row_start[i] = v;
    cursor[i] = v;
    if (i == n - 1) row_start[n] = N_EDGES;
}

__global__ void scatter_kernel(const int* __restrict__ rows, const int* __restrict__ cols,
                               const float* __restrict__ vals, int* __restrict__ cursor,
                               int2* __restrict__ ecv, int E) {
    int i = blockIdx.x * blockDim.x + threadIdx.x;
    if (i >= E) return;
    int r = rows[i];
    int p = atomicAdd(&cursor[r], 1);
    // plain cached store: random 8B scatter MUST go through L2 (NT store here
    // caused 8x write amplification, 103 MB HBM writes -> 122 us kernel)
    ecv[p] = make_int2(cols[i], __float_as_int(vals[i]));
}

// ---------------- GEMM v3: 64 full rows per block, A read fp32 direct ----
// 512 threads = 8 waves as 2(m) x 4(n); wave-tile 32x128; acc = 64 VGPR/lane.
// A traffic: each element read exactly once (full-row block). W staged via
// global_load_lds per 32-k chunk (L2-resident).
__global__ __launch_bounds__(512) void gemm_kernel(const float* __restrict__ A,
                                                   const bf16* __restrict__ B,
                                                   bf16* __restrict__ C) {
    __shared__ bf16 lB[512 * 32];  // 32 KB
    const int t = threadIdx.x;
    const int wave = t >> 6;
    const int lane = t & 63;
    const int rowBase = blockIdx.x * 64;
    const int wmBase = (wave >> 2) * 32;      // 2 m-groups of 32 rows
    const int wn = (wave & 3) * 128;          // 4 n-groups of 128 cols
    const int l15 = lane & 15;
    const int koct = (lane >> 4) * 8;         // k offset (8 elems) for frags

    floatx4 acc[2][8] = {};

    for (int k0 = 0; k0 < DIM; k0 += 32) {
        // stage W[0:512][k0:k0+32] -> lB[n][32]: 4 issues of 512 lanes x 16B
#pragma unroll
        for (int j = 0; j < 4; j++) {
            int idx = j * 512 + t;               // 0..2047
            int n = idx >> 2;
            int ko = (idx & 3) * 8;
            const bf16* g = B + (size_t)n * DIM + k0 + ko;
            bf16* l = lB + (size_t)j * 4096 + wave * 512;  // wave-uniform base
            __builtin_amdgcn_global_load_lds(
                (const __attribute__((address_space(1))) void*)g,
                (__attribute__((address_space(3))) void*)l, 16, 0, 0);
        }
        // A fragments: direct fp32 global load + cvt (each (row,k) used once)
        bf16x8 af[2];
#pragma unroll
        for (int i = 0; i < 2; i++) {
            int row = rowBase + wmBase + i * 16 + l15;
            if (row > N_NODES - 1) row = N_NODES - 1;
            const float* ga = A + (size_t)row * DIM + k0 + koct;
            float4 fa = *reinterpret_cast<const float4*>(ga);
            float4 fb = *reinterpret_cast<const float4*>(ga + 4);
            bf16x8 v;
            v[0] = (bf16)fa.x; v[1] = (bf16)fa.y; v[2] = (bf16)fa.z; v[3] = (bf16)fa.w;
            v[4] = (bf16)fb.x; v[5] = (bf16)fb.y; v[6] = (bf16)fb.z; v[7] = (bf16)fb.w;
            af[i] = v;
        }
        __syncthreads();   // staging complete
#pragma unroll
        for (int nt = 0; nt < 8; nt++) {
            const bf16* bp = lB + (size_t)(wn + nt * 16 + l15) * 32 + koct;
            bf16x8 bf = *reinterpret_cast<const bf16x8*>(bp);
            acc[0][nt] = __builtin_amdgcn_mfma_f32_16x16x32_bf16(af[0], bf, acc[0][nt], 0, 0, 0);
            acc[1][nt] = __builtin_amdgcn_mfma_f32_16x16x32_bf16(af[1], bf, acc[1][nt], 0, 0, 0);
        }
        __syncthreads();   // keep next staging from clobbering
    }
    // epilogue: D row = (lane>>4)*4+reg, col = lane&15
    const int rquad = (lane >> 4) * 4;
#pragma unroll
    for (int i = 0; i < 2; i++) {
#pragma unroll
        for (int reg = 0; reg < 4; reg++) {
            int gr = rowBase + wmBase + i * 16 + rquad + reg;
            if (gr >= N_NODES) continue;
#pragma unroll
            for (int nt = 0; nt < 8; nt++) {
                int gc = wn + nt * 16 + l15;
                C[(size_t)gr * DIM + gc] = (bf16)acc[i][nt][reg];
            }
        }
    }
}

// ---------------- SpMM: one wave per row, lane owns 8 dims (round-2 form) ----------------
__device__ __forceinline__ float blo(uint32_t w) { return __uint_as_float(w << 16); }
__device__ __forceinline__ float bhi(uint32_t w) { return __uint_as_float(w & 0xffff0000u); }

__device__ __forceinline__ void fmac8(float* acc, float v, const uint4& w) {
    acc[0] += v * blo(w.x); acc[1] += v * bhi(w.x);
    acc[2] += v * blo(w.y); acc[3] += v * bhi(w.y);
    acc[4] += v * blo(w.z); acc[5] += v * bhi(w.z);
    acc[6] += v * blo(w.w); acc[7] += v * bhi(w.w);
}

__global__ __launch_bounds__(256) void spmm_kernel(const int* __restrict__ row_start,
                                                   const int2* __restrict__ ecv,
                                                   const bf16* __restrict__ y,
                                                   float* __restrict__ y2) {
    const int wave = threadIdx.x >> 6;
    const int lane = threadIdx.x & 63;
    const int r = blockIdx.x * 4 + wave;  // grid = 12500 exactly -> r < 50000
    const int s = row_start[r];
    const int e = row_start[r + 1];
    float acc[8] = {0.f, 0.f, 0.f, 0.f, 0.f, 0.f, 0.f, 0.f};
    const uint32_t* yb = reinterpret_cast<const uint32_t*>(y);

    int i = s;
    for (; i + 3 < e; i += 4) {
        int2 e0 = ecv[i], e1 = ecv[i + 1], e2 = ecv[i + 2], e3 = ecv[i + 3];
        uint4 w0 = *reinterpret_cast<const uint4*>(yb + (size_t)e0.x * 256 + lane * 4);
        uint4 w1 = *reinterpret_cast<const uint4*>(yb + (size_t)e1.x * 256 + lane * 4);
        uint4 w2 = *reinterpret_cast<const uint4*>(yb + (size_t)e2.x * 256 + lane * 4);
        uint4 w3 = *reinterpret_cast<const uint4*>(yb + (size_t)e3.x * 256 + lane * 4);
        fmac8(acc, __int_as_float(e0.y), w0);
        fmac8(acc, __int_as_float(e1.y), w1);
        fmac8(acc, __int_as_float(e2.y), w2);
        fmac8(acc, __int_as_float(e3.y), w3);
    }
    for (; i < e; i++) {
        int2 e0 = ecv[i];
        uint4 w0 = *reinterpret_cast<const uint4*>(yb + (size_t)e0.x * 256 + lane * 4);
        fmac8(acc, __int_as_float(e0.y), w0);
    }
    float4* out = reinterpret_cast<float4*>(y2 + (size_t)r * DIM + lane * 8);
    out[0] = make_float4(acc[0], acc[1], acc[2], acc[3]);
    out[1] = make_float4(acc[4], acc[5], acc[6], acc[7]);
}

// ---------------- reduction: colsum[512] + total sum of squares ----------------
__global__ __launch_bounds__(256) void reduce_kernel(const float* __restrict__ y2,
                                                     float* __restrict__ colsum,
                                                     float* __restrict__ totsq) {
    const int t = threadIdx.x;
    const int d2 = t * 2;
    float c0 = 0.f, c1 = 0.f, sq = 0.f;
    for (int r = blockIdx.x; r < N_NODES; r += gridDim.x) {
        floatx2 v = __builtin_nontemporal_load(
            reinterpret_cast<const floatx2*>(y2 + (size_t)r * DIM + d2));
        c0 += v[0]; c1 += v[1];
        sq += v[0] * v[0] + v[1] * v[1];
    }
    atomicAdd(&colsum[d2], c0);
    atomicAdd(&colsum[d2 + 1], c1);
    __shared__ float ssq[256];
    ssq[t] = sq;
    __syncthreads();
    for (int off = 128; off > 0; off >>= 1) {
        if (t < off) ssq[t] += ssq[t + off];
        __syncthreads();
    }
    if (t == 0) atomicAdd(totsq, ssq[0]);
}

__global__ void scalar_kernel(const float* __restrict__ colsum, const float* __restrict__ totsq,
                              const float* __restrict__ scale, float* __restrict__ sfac) {
    __shared__ float sm[512];
    const int t = threadIdx.x;
    float mu = colsum[t] * (1.0f / N_NODES);
    sm[t] = mu * mu;
    __syncthreads();
    for (int off = 256; off > 0; off >>= 1) {
        if (t < off) sm[t] += sm[t + off];
        __syncthreads();
    }
    if (t == 0) {
        float var = totsq[0] * (1.0f / N_NODES) - sm[0];
        sfac[0] = rsqrtf(var) * (1.0f + scale[0]) * sqrtf((float)DIM);
    }
}

// ---------------- final: out = relu((y2 - mu) * s) + x  (in place on d_out) ----------------
__global__ void final_kernel(float* __restrict__ y2, const float* __restrict__ x,
                             const float* __restrict__ colsum, const float* __restrict__ sfac,
                             int n4) {
    int i = blockIdx.x * blockDim.x + threadIdx.x;
    if (i >= n4) return;
    const float invN = 1.0f / N_NODES;
    floatx4 v = __builtin_nontemporal_load(reinterpret_cast<floatx4*>(y2) + i);
    floatx4 xv = __builtin_nontemporal_load(reinterpret_cast<const floatx4*>(x) + i);
    float4 mu = reinterpret_cast<const float4*>(colsum)[i & 127];
    float s = sfac[0];
    v[0] = fmaxf((v[0] - mu.x * invN) * s, 0.0f) + xv[0];
    v[1] = fmaxf((v[1] - mu.y * invN) * s, 0.0f) + xv[1];
    v[2] = fmaxf((v[2] - mu.z * invN) * s, 0.0f) + xv[2];
    v[3] = fmaxf((v[3] - mu.w * invN) * s, 0.0f) + xv[3];
    __builtin_nontemporal_store(v, reinterpret_cast<floatx4*>(y2) + i);
}

extern "C" void kernel_launch(void* const* d_in, const int* in_sizes, int n_in,
                              void* d_out, int out_size, void* d_ws, size_t ws_size,
                              hipStream_t stream) {
    const float* x        = (const float*)d_in[0];
    const int*   adj_rows = (const int*)d_in[1];
    const int*   adj_cols = (const int*)d_in[2];
    const float* adj_vals = (const float*)d_in[3];
    const float* weight   = (const float*)d_in[4];
    const float* scale    = (const float*)d_in[5];
    float* out = (float*)d_out;  // doubles as y2 buffer

    char* ws = (char*)d_ws;
    size_t off = 0;
    auto alloc = [&](size_t b) {
        char* p = ws + off;
        off += (b + 255) & ~(size_t)255;
        return p;
    };
    const int nblk = (NB + 1023) / 1024;  // 49
    bf16*  y         = (bf16*)alloc((size_t)N_NODES * DIM * 2);        // 51.2 MB
    int2*  ecv       = (int2*)alloc((size_t)N_EDGES * 8);              // 12.8 MB
    bf16*  Wb        = (bf16*)alloc((size_t)DIM * DIM * 2);            // 0.5 MB
    int*   cnt       = (int*)alloc((size_t)NB * 4);                    // 200 KB
    int*   cursor    = cnt;   // ALIAS: cnt dead after scanA; cursor born in scanC
    int*   row_start = (int*)alloc((size_t)(NB + 1) * 4);
    int*   blksum    = (int*)alloc((size_t)nblk * 4);
    int*   blkoff    = (int*)alloc((size_t)nblk * 4);
    float* stats     = (float*)alloc(514 * 4);  // colsum[512] | totsq | sfac
    float* colsum    = stats;
    float* totsq     = stats + 512;
    float* sfac      = stats + 513;
    (void)ws_size; (void)in_sizes; (void)n_in; (void)out_size;

    hipMemsetAsync(cnt, 0, (size_t)NB * 4, stream);
    hipMemsetAsync(stats, 0, 514 * 4, stream);

    const int n4x = N_NODES * DIM / 4;  // 6,400,000
    const int n4w = DIM * DIM / 4;      // 65,536
    cast_kernel<<<(n4w + 255) / 256, 256, 0, stream>>>(weight, Wb, n4w);

    hist_kernel<<<(N_EDGES + 255) / 256, 256, 0, stream>>>(adj_rows, cnt, N_EDGES);
    scanA_kernel<<<nblk, 1024, 0, stream>>>(cnt, row_start, blksum, NB);
    scanB_kernel<<<1, 1024, 0, stream>>>(blksum, blkoff, nblk);
    scanC_kernel<<<nblk, 1024, 0, stream>>>(row_start, blkoff, cursor, NB);
    scatter_kernel<<<(N_EDGES + 255) / 256, 256, 0, stream>>>(adj_rows, adj_cols, adj_vals,
                                                              cursor, ecv, N_EDGES);

    gemm_kernel<<<(N_NODES + 63) / 64, 512, 0, stream>>>(x, Wb, y);

    spmm_kernel<<<N_NODES / 4, 256, 0, stream>>>(row_start, ecv, y, out);

    reduce_kernel<<<512, 256, 0, stream>>>(out, colsum, totsq);
    scalar_kernel<<<1, 512, 0, stream>>>(colsum, totsq, scale, sfac);
    final_kernel<<<(n4x + 255) / 256, 256, 0, stream>>>(out, x, colsum, sfac, n4x);
}